// Round 1
// 260.578 us; speedup vs baseline: 1.0610x; 1.0610x over previous
//
#include <hip/hip_runtime.h>

constexpr int Zn = 20000;
constexpr int Un = 128;
constexpr int Sn = 8;
constexpr int Pn = 64;
constexpr int ROW = Sn * Un;          // 1024 floats per (z, tensor)
constexpr int ZPB = 2;                // z rows per block
constexpr int THREADS = 256;          // 4 waves; wave w owns segments {2w, 2w+1}

// ---------------------------------------------------------------------------
// Prep: one wave, one lane per path. Counting-sort by i3 via ballot/popc —
// no dynamically-indexed local arrays (those go to scratch = HBM latency).
// Table entries hold LDS float offsets for layout [t][z][1024] and coef.
// ---------------------------------------------------------------------------
__global__ __launch_bounds__(64) void prep_kernel(const int* __restrict__ pi,
                                                  const float* __restrict__ pc,
                                                  int4* __restrict__ table,
                                                  int* __restrict__ segstart) {
    const int p = threadIdx.x & 63;
    const int i0 = pi[4 * p + 0];
    const int i1 = pi[4 * p + 1];
    const int i2 = pi[4 * p + 2];
    const int i3 = pi[4 * p + 3];
    const float w = pc[p];
    const unsigned long long below = (1ull << p) - 1ull;

    int base = 0, slot = 0;
#pragma unroll
    for (int s = 0; s < Sn; ++s) {
        unsigned long long m = __ballot(i3 == s);
        if (i3 == s) slot = base + __popcll(m & below);
        if (p == 0) segstart[s] = base;
        base += __popcll(m);
    }
    if (p == 0) segstart[Sn] = base;   // == 64

    table[slot] = make_int4(i0 * Un,                    // tensor0: offset 0
                            ZPB * ROW + i1 * Un,        // tensor1 block base
                            2 * ZPB * ROW + i2 * Un,    // tensor2 block base
                            __float_as_int(w));
}

// ---------------------------------------------------------------------------
// Main: stage 2 z x 3 tensors (24 KB LDS -> 6 blocks/CU x 4 waves = 24
// waves/CU, 2x the old residency). Within a wave: zloc = lane>>5,
// u4 = lane&31 (float4 channel). Wave w computes segments {2w, 2w+1} in ONE
// flat loop over its contiguous (i3-sorted) table range, with dual
// accumulators selected by a wave-uniform compare -> no loop restart between
// segments, ~16-deep pipeline. The next table entry is prefetched each
// iteration through readfirstlane (wave-uniform -> SMEM path), so the
// table load -> ds_read -> fma chain of iteration k+1 overlaps iteration k.
// ---------------------------------------------------------------------------
__global__ __launch_bounds__(THREADS, 6) void tp_kernel(
        const float* __restrict__ x0,
        const float* __restrict__ x1,
        const float* __restrict__ x2,
        const int4* __restrict__ table,
        const int* __restrict__ segstart,
        float* __restrict__ out) {
    __shared__ __align__(16) float lds[3 * ZPB * ROW];   // 24 KB, [t][z][1024]
    const int tid = threadIdx.x;
    const int zblk = blockIdx.x * ZPB;

    // ---- Stage: layout [t][z][row], fully coalesced float4 ----
#pragma unroll
    for (int t = 0; t < 3; ++t) {
        const float4* src = (const float4*)(t == 0 ? x0 : (t == 1 ? x1 : x2));
        float4* dst = (float4*)lds + t * (ZPB * ROW / 4);
#pragma unroll
        for (int i = 0; i < (ZPB * ROW / 4) / THREADS; ++i) {   // 2 iters
            int local = i * THREADS + tid;       // 0..511 float4
            int z = local >> 8;                  // /256 float4 per row
            int r = local & 255;
            dst[local] = src[(size_t)(zblk + z) * (ROW / 4) + r];
        }
    }

    const int lane = tid & 63;
    const int wave = tid >> 6;                   // 0..3: two segments each
    const int zloc = lane >> 5;                  // 0,1
    const int u4   = lane & 31;                  // float4 slot in 128-float row
    const int s0   = wave * 2;

    // Wave-uniform segment bounds (tiny, L2-hot).
    const int kbeg = segstart[s0];
    const int kmid = segstart[s0 + 1];
    const int kend = segstart[s0 + 2];

    __syncthreads();

    const float* zb = lds + zloc * ROW;          // + e.{x,y,z} selects tensor/row
    float4 acc0 = make_float4(0.f, 0.f, 0.f, 0.f);
    float4 acc1 = make_float4(0.f, 0.f, 0.f, 0.f);

    // Prefetched table entry (guard the k==kend empty case against OOB).
    int4 e = table[__builtin_amdgcn_readfirstlane(kbeg < kend ? kbeg : 0)];
    for (int k = kbeg; k < kend; ++k) {
        const int kn = (k + 1 < kend) ? k + 1 : k;
        const int4 en = table[__builtin_amdgcn_readfirstlane(kn)];

        const float4 a = *(const float4*)(zb + e.x + u4 * 4);
        const float4 b = *(const float4*)(zb + e.y + u4 * 4);
        const float4 c = *(const float4*)(zb + e.z + u4 * 4);
        const float w  = __int_as_float(e.w);
        const float w0 = (k < kmid) ? w : 0.f;   // wave-uniform select
        const float w1 = (k < kmid) ? 0.f : w;

        float4 p;
        p.x = a.x * b.x * c.x;
        p.y = a.y * b.y * c.y;
        p.z = a.z * b.z * c.z;
        p.w = a.w * b.w * c.w;
        acc0.x = fmaf(p.x, w0, acc0.x);
        acc0.y = fmaf(p.y, w0, acc0.y);
        acc0.z = fmaf(p.z, w0, acc0.z);
        acc0.w = fmaf(p.w, w0, acc0.w);
        acc1.x = fmaf(p.x, w1, acc1.x);
        acc1.y = fmaf(p.y, w1, acc1.y);
        acc1.z = fmaf(p.z, w1, acc1.z);
        acc1.w = fmaf(p.w, w1, acc1.w);

        e = en;
    }

    float* orow = out + (size_t)(zblk + zloc) * ROW;
    *(float4*)(orow + s0 * Un + u4 * 4) = acc0;
    *(float4*)(orow + (s0 + 1) * Un + u4 * 4) = acc1;
}

extern "C" void kernel_launch(void* const* d_in, const int* in_sizes, int n_in,
                              void* d_out, int out_size, void* d_ws, size_t ws_size,
                              hipStream_t stream) {
    const float* x0 = (const float*)d_in[0];
    const float* x1 = (const float*)d_in[1];
    const float* x2 = (const float*)d_in[2];
    const float* pc = (const float*)d_in[3];
    const int*   pi = (const int*)d_in[4];
    float* out = (float*)d_out;

    int4* table    = (int4*)d_ws;
    int*  segstart = (int*)((char*)d_ws + Pn * sizeof(int4));

    prep_kernel<<<1, 64, 0, stream>>>(pi, pc, table, segstart);
    tp_kernel<<<Zn / ZPB, THREADS, 0, stream>>>(x0, x1, x2, table, segstart, out);
}